// Round 16
// baseline (199.667 us; speedup 1.0000x reference)
//
#include <hip/hip_runtime.h>
#include <math.h>

typedef unsigned short u16;
typedef unsigned int   u32;
typedef unsigned char  u8;
typedef __attribute__((ext_vector_type(8))) short short8;
typedef __attribute__((ext_vector_type(4))) float f32x4;
typedef __attribute__((ext_vector_type(4))) unsigned short ushort4_t;

// GeoMamba: B=8, L=39, D=256, K=5, M=252
constexpr int cB   = 8;
constexpr int cL   = 39;
constexpr int cD   = 256;
constexpr int cDD  = 65536;   // D*D
constexpr int cM   = 252;
constexpr int cMM  = 63504;   // M*M
constexpr int PAIRS = cL * cL; // 1521

constexpr int GCHUNKS = 256;   // gram chunks per batch (256 px each)
constexpr int GKP     = 65536; // tile-major K for out-gemm (fp8 bytes per row)
constexpr int CSTEP   = 512;   // K per gemm block
constexpr int GSPLIT  = 128;   // 128*512 = 65536
constexpr int PROW    = 40;    // u16 per pixel row of hst
constexpr int WSTR    = 36;    // padded LDS row stride (u16) for conv weight tiles
constexpr int TSTR    = 280;   // gram LDS transpose row stride (u16)

// ---- ws layout (float offsets) ----
constexpr size_t OFF_SP   = 0;                          // gram partials [B][256][1521]
constexpr size_t SZ_SP    = (size_t)cB * GCHUNKS * PAIRS;
constexpr size_t OFF_TS   = 0;                          // overlaps SP (dead after spred)
constexpr size_t OFF_ATTN = OFF_SP + SZ_SP;             // (spare)
constexpr size_t SZ_ATTN  = (size_t)cB * PAIRS;
constexpr size_t OFF_SCD  = OFF_ATTN + SZ_ATTN;         // reduced scores [B][1521]
constexpr size_t SZ_SCD   = (size_t)cB * PAIRS;
constexpr size_t OFF_W2M  = OFF_SCD + SZ_SCD;           // main wts bf16 [B][tap25][oc48][32]
constexpr size_t SZ_W2M   = (size_t)cB * 25 * 48 * 32 / 2;
constexpr size_t OFF_W2T  = OFF_W2M + SZ_W2M;           // tail wts bf16 [B][kc7][oc48][32]
constexpr size_t SZ_W2T   = (size_t)cB * 7 * 48 * 32 / 2;
constexpr size_t OFF_HST  = OFF_W2T + SZ_W2T;           // hst bf16 [B][65536][40]; op overlaps
constexpr size_t SZ_HST   = (size_t)cB * 65536 * PROW / 2;
constexpr size_t SZ_OP    = (size_t)GSPLIT * 312 * 256;
static_assert(SZ_OP <= SZ_HST, "op must fit inside hst region");
constexpr size_t OFF_CONV = OFF_HST + SZ_HST;           // exp(conv) fp8 [312][GKP] tile-major
constexpr size_t SZ_CONV  = (size_t)312 * GKP / 4;
constexpr size_t OFF_OWB  = OFF_CONV + SZ_CONV;         // out_w fp8*256 [256][GKP] tile-major
constexpr size_t SZ_OWB   = (size_t)256 * GKP / 4;
constexpr size_t WS_FLOATS = OFF_OWB + SZ_OWB;          // ~92.5 MB

__device__ inline u16 f2bf(float x) {
    union { float f; unsigned u; } v; v.f = x;
    unsigned r = v.u + 0x7fffu + ((v.u >> 16) & 1u);   // RNE
    return (u16)(r >> 16);
}
__device__ inline u8 f2fp8(float x) {
    return (u8)(__builtin_amdgcn_cvt_pk_fp8_f32(x, x, 0, false) & 0xff);
}

// ---------------------------------------------------------------------------
// K0a: cast out_w*256 -> fp8 e4m3, gathered into tile-major K layout.
// ---------------------------------------------------------------------------
__global__ __launch_bounds__(256) void k_bwcast(const float* __restrict__ ow,
                                                u8* __restrict__ owb) {
    const int o = blockIdx.x;
    const float* src = ow + (size_t)o * cMM;
    u8* dst = owb + (size_t)o * GKP;
    for (int k4 = threadIdx.x; k4 < GKP / 4; k4 += 256) {
        const int k = k4 * 4;
        const int tile = k >> 8, loc = k & 255;
        const int th = tile >> 4, tw = tile & 15;
        const int ph = loc >> 4, pw = loc & 15;
        const int oh = th*16 + ph, owc = tw*16 + pw;
        unsigned r = 0;
        if (oh < cM && owc + 3 < cM) {
            const float4 f = *(const float4*)(src + oh*cM + owc);
            unsigned lo = (unsigned)__builtin_amdgcn_cvt_pk_fp8_f32(f.x*256.f, f.y*256.f, 0, false);
            unsigned hi = (unsigned)__builtin_amdgcn_cvt_pk_fp8_f32(f.z*256.f, f.w*256.f, 0, false);
            r = (lo & 0xffffu) | (hi << 16);
        }
        *(unsigned*)(dst + k) = r;
    }
}

// ---------------------------------------------------------------------------
// K1: fused hst-transpose + MFMA gram (verified round 12/13).
// ---------------------------------------------------------------------------
__global__ __launch_bounds__(256) void k_hstgram(const float* __restrict__ hs,
                                                 u16* __restrict__ hst,
                                                 float* __restrict__ sp) {
    const int b   = blockIdx.y;
    const int ck  = blockIdx.x;
    const int tid = threadIdx.x;
    const int wv = tid >> 6, ln15 = tid & 15, kg4 = (tid & 63) >> 4;
    const int px = ck * 256 + tid;

    __shared__ __align__(16) u8 smem[4 * 48 * 50 * 4];   // 38400 B (R) >= T 26880 B
    u16 (*T)[TSTR] = (u16 (*)[TSTR])smem;

    const float* hb = hs + (size_t)b * (cL * cDD) + px;
    u32 w[20];
    #pragma unroll
    for (int c2 = 0; c2 < 20; ++c2) {
        const int c0 = 2*c2, c1 = 2*c2 + 1;
        const u32 lo = f2bf(hb[(size_t)c0 * cDD]);
        const u32 hi = (c1 < cL) ? (u32)f2bf(hb[(size_t)c1 * cDD]) : 0u;
        w[c2] = lo | (hi << 16);
    }
    // (a) hst store [px][40]
    u16* ob = hst + (size_t)b * (65536 * PROW) + (size_t)px * PROW;
    #pragma unroll
    for (int g = 0; g < 5; ++g) {
        uint4 v;
        v.x = w[g*4 + 0]; v.y = w[g*4 + 1]; v.z = w[g*4 + 2]; v.w = w[g*4 + 3];
        *(uint4*)(ob + g*8) = v;
    }
    // (b) LDS transpose; zero pad rows 39..47
    {
        u16* Tf = (u16*)smem;
        for (int i = tid; i < 9 * TSTR; i += 256) Tf[39*TSTR + i] = 0;
    }
    #pragma unroll
    for (int c2 = 0; c2 < 20; ++c2) {
        T[2*c2][tid] = (u16)w[c2];
        if (2*c2 + 1 < cL) T[2*c2 + 1][tid] = (u16)(w[c2] >> 16);
    }
    __syncthreads();

    f32x4 acc[3][3] = {};
    #pragma unroll
    for (int s = 0; s < 2; ++s) {
        const int pxl = wv*64 + s*32 + kg4*8;
        short8 f[3];
        #pragma unroll
        for (int o = 0; o < 3; ++o)
            f[o] = *(const short8*)&T[o*16 + ln15][pxl];
        #pragma unroll
        for (int oi = 0; oi < 3; ++oi)
            #pragma unroll
            for (int oj = 0; oj < 3; ++oj)
                acc[oi][oj] = __builtin_amdgcn_mfma_f32_16x16x32_bf16(
                    f[oi], f[oj], acc[oi][oj], 0, 0, 0);
    }
    __syncthreads();                       // T reads done; alias as R

    float (*R)[48 * 50] = (float (*)[48 * 50])smem;
    #pragma unroll
    for (int oi = 0; oi < 3; ++oi)
        #pragma unroll
        for (int oj = 0; oj < 3; ++oj)
            #pragma unroll
            for (int r = 0; r < 4; ++r)
                R[wv][(oi*16 + kg4*4 + r)*50 + oj*16 + ln15] = acc[oi][oj][r];
    __syncthreads();

    float* outp = sp + ((size_t)b * GCHUNKS + ck) * PAIRS;
    for (int idx = tid; idx < PAIRS; idx += 256) {
        const int i = idx / 39, j = idx - i * 39;
        const int a = i * 50 + j;
        outp[idx] = R[0][a] + R[1][a] + R[2][a] + R[3][a];
    }
}

// ---------------------------------------------------------------------------
// K1b: parallel reduce of gram partials: scd[b][pair] = sum_c sp[b][c][pair].
// ---------------------------------------------------------------------------
__global__ __launch_bounds__(256) void k_spred(const float* __restrict__ sp,
                                               float* __restrict__ scd) {
    const int b = blockIdx.y, pg = blockIdx.x;
    const int lane = threadIdx.x & 63, cs = threadIdx.x >> 6;
    const int pair = pg*64 + lane;
    float s = 0.f;
    if (pair < PAIRS) {
        const float* base = sp + ((size_t)b*GCHUNKS + cs*64)*PAIRS + pair;
        #pragma unroll 8
        for (int c = 0; c < 64; ++c) s += base[(size_t)c * PAIRS];
    }
    __shared__ float red[4][64];
    red[cs][lane] = s;
    __syncthreads();
    if (threadIdx.x < 64) {
        const int p = pg*64 + threadIdx.x;
        if (p < PAIRS)
            scd[(size_t)b*PAIRS + p] = red[0][threadIdx.x] + red[1][threadIdx.x]
                                     + red[2][threadIdx.x] + red[3][threadIdx.x];
    }
}

// ---------------------------------------------------------------------------
// K2: fused softmax + weight-fold. grid B, 1024 thr.
// ---------------------------------------------------------------------------
__global__ __launch_bounds__(1024) void k_smwt(const float* __restrict__ scd,
                                               const float* __restrict__ cw,
                                               float* __restrict__ outAttn,
                                               u16* __restrict__ w2m,
                                               u16* __restrict__ w2t) {
    const int b = blockIdx.x;
    const int t = threadIdx.x;
    __shared__ float sc[PAIRS];
    for (int idx = t; idx < PAIRS; idx += 1024)
        sc[idx] = scd[(size_t)b*PAIRS + idx] * (1.0f / 256.0f);
    u32* zm = (u32*)(w2m + (size_t)b * 25*48*32);
    u32* zt = (u32*)(w2t + (size_t)b * 7*48*32);
    for (int i = t; i < 25*48*16; i += 1024) zm[i] = 0;
    for (int i = t; i < 7*48*16;  i += 1024) zt[i] = 0;
    __syncthreads();
    if (t < cL) {
        const int i = t;
        float m = -1e30f;
        #pragma unroll
        for (int j = 0; j < cL; ++j) m = fmaxf(m, sc[i*cL + j]);
        float e[cL];
        float sum = 0.f;
        #pragma unroll
        for (int j = 0; j < cL; ++j) { e[j] = expf(sc[i*cL + j] - m); sum += e[j]; }
        const float inv = 1.0f / sum;
        #pragma unroll
        for (int j = 0; j < cL; ++j) {
            const float a = e[j] * inv;
            sc[i*cL + j] = a;
            outAttn[(size_t)b*PAIRS + i*cL + j] = a;
        }
    }
    __syncthreads();
    if (t < cL * 25) {
        const int oc = t / 25, tap = t % 25;
        float c[cL];
        #pragma unroll
        for (int i = 0; i < cL; ++i)
            c[i] = cw[(size_t)oc * (cL*25) + i*25 + tap];
        u16* dm = w2m + ((size_t)(b*25 + tap)*48 + oc)*32;
        u16* dt = w2t + ((size_t)(b*7 + (tap>>2))*48 + oc)*32 + (tap&3)*8;
        for (int j = 0; j < cL; ++j) {
            float a = 0.f;
            #pragma unroll
            for (int i = 0; i < cL; ++i) a = fmaf(c[i], sc[i*cL + j], a);
            if (j < 32) dm[j] = f2bf(a);
            else        dt[j - 32] = f2bf(a);
        }
    }
}

// ---------------------------------------------------------------------------
// K4: conv as dense-K MFMA with LDS weight broadcast (round-13 structure)
// + 1-bit P swizzle: slots 0..3 at u16-offset (slot*8 ^ (p&8)). Separates
// the ln15 <-> ln15+8 bank-span collision (8-way -> ~4-way) while leaving
// the per-row staging-write span set unchanged. Tail slot 4 fixed.
// ---------------------------------------------------------------------------
__global__ __launch_bounds__(256, 4) void k_conv(const u16* __restrict__ hst,
                                                 const u16* __restrict__ w2m,
                                                 const u16* __restrict__ w2t,
                                                 const float* __restrict__ cb,
                                                 u8* __restrict__ convout,
                                                 float* __restrict__ tileSumsq) {
    const int b   = blockIdx.z;
    const int gh0 = blockIdx.y * 16, gw0 = blockIdx.x * 16;
    const int tid = threadIdx.x;
    const int wv  = tid >> 6;
    const int ln15 = tid & 15;
    const int kg4  = (tid & 63) >> 4;

    __shared__ u16 P[400 * PROW];      // 32000 B; reused as fp8 staging
    __shared__ u16 W[2][48 * WSTR];    // 2 x 3456 B weight broadcast tiles
    __shared__ float red[4][48];

    const u16* wbm = w2m + (size_t)b * 25*48*32;
    const u16* wbt = w2t + (size_t)b * 7*48*32;
    const bool wact = tid < 192;
    const int  wrow = tid >> 2, wq = tid & 3;

    uint4 wA = {};
    if (wact) wA = *(const uint4*)(wbm + tid*8);

    const u16* hb = hst + (size_t)b * (65536 * PROW);
    for (int c = tid; c < 2000; c += 256) {
        const int p = c / 5, g = c - p*5;
        const int pr = p / 20, pc = p - pr*20;
        const int gh = min(gh0 + pr, 255);
        const size_t pix = (size_t)gh * 256 + gw0 + pc;   // may spill; masked later
        const short8 v = *(const short8*)(hb + pix*PROW + g*8);
        const int off = (g < 4) ? ((g*8) ^ (p & 8)) : 32;
        *(short8*)&P[p*PROW + off] = v;
    }
    if (wact) {
        *(uint4*)&W[0][wrow*WSTR + wq*8] = wA;
        wA = *(const uint4*)(wbm + 1*48*32 + tid*8);
    }
    __syncthreads();

    f32x4 acc[3][4] = {};
    const int kg48 = kg4 * 8;

    #pragma unroll
    for (int t = 0; t < 32; ++t) {
        const int cur = t & 1;
        if (t + 1 < 32 && wact)
            *(uint4*)&W[cur ^ 1][wrow*WSTR + wq*8] = wA;
        if (t + 2 < 32 && wact) {
            const int c2 = t + 2;
            const u16* ws = (c2 < 25) ? (wbm + (size_t)c2 * 48*32)
                                      : (wbt + (size_t)(c2 - 25) * 48*32);
            wA = *(const uint4*)(ws + tid*8);
        }
        short8 af0 = *(const short8*)&W[cur][( 0 + ln15)*WSTR + kg48];
        short8 af1 = *(const short8*)&W[cur][(16 + ln15)*WSTR + kg48];
        short8 af2 = *(const short8*)&W[cur][(32 + ln15)*WSTR + kg48];
        if (t < 25) {
            const int kh = t / 5, kw = t - (t/5)*5;
            #pragma unroll
            for (int pt = 0; pt < 4; ++pt) {
                const int p = (wv*4 + pt + kh)*20 + ln15 + kw;
                const short8 bfr = *(const short8*)&P[p*PROW + (kg48 ^ (p & 8))];
                acc[0][pt] = __builtin_amdgcn_mfma_f32_16x16x32_bf16(af0, bfr, acc[0][pt], 0, 0, 0);
                acc[1][pt] = __builtin_amdgcn_mfma_f32_16x16x32_bf16(af1, bfr, acc[1][pt], 0, 0, 0);
                acc[2][pt] = __builtin_amdgcn_mfma_f32_16x16x32_bf16(af2, bfr, acc[2][pt], 0, 0, 0);
            }
        } else {
            int tap = (t - 25)*4 + kg4;
            if (tap > 24) tap = 24;
            const int kh = tap / 5, kw = tap - kh*5;
            #pragma unroll
            for (int pt = 0; pt < 4; ++pt) {
                const int p = (wv*4 + pt + kh)*20 + ln15 + kw;
                const short8 bfr = *(const short8*)&P[p*PROW + 32];
                acc[0][pt] = __builtin_amdgcn_mfma_f32_16x16x32_bf16(af0, bfr, acc[0][pt], 0, 0, 0);
                acc[1][pt] = __builtin_amdgcn_mfma_f32_16x16x32_bf16(af1, bfr, acc[1][pt], 0, 0, 0);
                acc[2][pt] = __builtin_amdgcn_mfma_f32_16x16x32_bf16(af2, bfr, acc[2][pt], 0, 0, 0);
            }
        }
        __syncthreads();
    }

    u8* E = (u8*)P;                   // E[oc][256] fp8 staging

    float ss[3][4];
    #pragma unroll
    for (int o = 0; o < 3; ++o)
        #pragma unroll
        for (int r = 0; r < 4; ++r) ss[o][r] = 0.f;

    const int tile = blockIdx.y * 16 + blockIdx.x;
    const int ow = gw0 + ln15;
    #pragma unroll
    for (int o = 0; o < 3; ++o) {
        #pragma unroll
        for (int r = 0; r < 4; ++r) {
            const int oc = o*16 + kg4*4 + r;
            const float bias = (oc < cL) ? cb[oc] : 0.f;
            #pragma unroll
            for (int pt = 0; pt < 4; ++pt) {
                const int oh = gh0 + wv*4 + pt;
                const int loc = (wv*4 + pt)*16 + ln15;
                u8 val = 0;
                if (oc < cL && oh < cM && ow < cM) {
                    const float e = __expf(acc[o][pt][r] + bias);
                    if (ow <= oh) val = f2fp8(e);
                    ss[o][r] += e * e;
                }
                if (oc < cL) E[oc*256 + loc] = val;
            }
        }
    }
    __syncthreads();

    for (int c = tid; c < cL*16; c += 256) {
        const int oc = c >> 4, seg = c & 15;
        const uint4 v = *(const uint4*)&E[oc*256 + seg*16];
        *(uint4*)&convout[(size_t)(b*cL + oc)*GKP + tile*256 + seg*16] = v;
    }

    #pragma unroll
    for (int o = 0; o < 3; ++o) {
        #pragma unroll
        for (int r = 0; r < 4; ++r) {
            float v = ss[o][r];
            v += __shfl_xor(v, 1);
            v += __shfl_xor(v, 2);
            v += __shfl_xor(v, 4);
            v += __shfl_xor(v, 8);
            if (ln15 == 0) red[wv][o*16 + kg4*4 + r] = v;
        }
    }
    __syncthreads();
    if (tid < cL) {
        tileSumsq[((size_t)b*256 + tile)*cL + tid] =
            red[0][tid] + red[1][tid] + red[2][tid] + red[3][tid];
    }
}

// ---------------------------------------------------------------------------
// K5: fp8 MFMA out-GEMM. grid (1, 3, 128), 512 thr; block tile 128x256,
// wave tile 64x64; double-buffered LDS, rows padded to 80 B.
// ---------------------------------------------------------------------------
__global__ __launch_bounds__(512) void k_gemm(const u8* __restrict__ A,
                                              const u8* __restrict__ Bw,
                                              float* __restrict__ op) {
    const int mt = blockIdx.y, z = blockIdx.z;
    const int tid = threadIdx.x;
    const int wid = tid >> 6, lane = tid & 63;
    const int ln15 = lane & 15, kg4 = lane >> 4;
    const int wm = wid >> 2, wn = wid & 3;

    __shared__ u8 As[2][128*80];
    __shared__ u8 Bs[2][256*80];

    const int mbase = mt * 128;
    const int ra = tid >> 2, sl = tid & 3;
    const int arow = mbase + ra;
    const int aro = (arow < 312) ? arow : 0;
    const u8* Ap  = A  + (size_t)aro * GKP        + z*CSTEP + sl*16;
    const u8* Bp0 = Bw + (size_t)ra * GKP         + z*CSTEP + sl*16;
    const u8* Bp1 = Bw + (size_t)(128 + ra) * GKP + z*CSTEP + sl*16;

    uint4 pa  = *(const uint4*)Ap;
    uint4 pb0 = *(const uint4*)Bp0;
    uint4 pb1 = *(const uint4*)Bp1;

    f32x4 acc[4][4] = {};

    for (int s = 0; s < CSTEP/64; ++s) {
        const int cur = s & 1;
        __syncthreads();
        *(uint4*)&As[cur][ra*80 + sl*16]        = pa;
        *(uint4*)&Bs[cur][ra*80 + sl*16]        = pb0;
        *(uint4*)&Bs[cur][(128 + ra)*80 + sl*16] = pb1;
        __syncthreads();
        if (s + 1 < CSTEP/64) {
            const int off = (s + 1) * 64;
            pa  = *(const uint4*)(Ap + off);
            pb0 = *(const uint4*)(Bp0 + off);
            pb1 = *(const uint4*)(Bp1 + off);
        }
        #pragma unroll
        for (int kc = 0; kc < 2; ++kc) {
            long af[4], bf[4];
            #pragma unroll
            for (int fm = 0; fm < 4; ++fm)
                af[fm] = *(const long*)&As[cur][(wm*64 + fm*16 + ln15)*80 + kc*32 + kg4*8];
            #pragma unroll
            for (int fn = 0; fn < 4; ++fn)
                bf[fn] = *(const long*)&Bs[cur][(wn*64 + fn*16 + ln15)*80 + kc*32 + kg4*8];
            #pragma unroll
            for (int fm = 0; fm < 4; ++fm)
                #pragma unroll
                for (int fn = 0; fn < 4; ++fn)
                    acc[fm][fn] = __builtin_amdgcn_mfma_f32_16x16x32_fp8_fp8(
                        af[fm], bf[fn], acc[fm][fn], 0, 0, 0);
        }
    }

    #pragma unroll
    for (int fm = 0; fm < 4; ++fm) {
        #pragma unroll
        for (int r = 0; r < 4; ++r) {
            const int row = mbase + wm*64 + fm*16 + kg4*4 + r;
            if (row < 312) {
                #pragma unroll
                for (int fn = 0; fn < 4; ++fn) {
                    const int col = wn*64 + fn*16 + ln15;
                    op[((size_t)z*312 + row)*256 + col] = acc[fm][fn][r];
                }
            }
        }
    }
}

// ---------------------------------------------------------------------------
// K5b: fused norm + finish. grid 312.
// ---------------------------------------------------------------------------
__global__ __launch_bounds__(256) void k_finish(const float* __restrict__ ts,
                                                const float* __restrict__ op,
                                                float* __restrict__ out) {
    const int row = blockIdx.x;                // b*39 + l
    const int b = row / cL, l = row - b*cL;
    const int tid = threadIdx.x;

    float v = ts[((size_t)b*256 + tid)*cL + l];
    for (int off = 32; off; off >>= 1) v += __shfl_down(v, off, 64);
    __shared__ float r[4];
    __shared__ float nrm;
    if ((tid & 63) == 0) r[tid >> 6] = v;
    __syncthreads();
    if (tid == 0) nrm = sqrtf(r[0] + r[1] + r[2] + r[3]) * 256.0f;
    __syncthreads();

    const int idx = row * 256 + tid;
    float s = 0.f;
    for (int z = 0; z < GSPLIT; ++z) s += op[(size_t)z * (312*256) + idx];
    out[idx] = s / nrm;
}

// ---------------------------------------------------------------------------
extern "C" void kernel_launch(void* const* d_in, const int* in_sizes, int n_in,
                              void* d_out, int out_size, void* d_ws, size_t ws_size,
                              hipStream_t stream) {
    const float* hs = (const float*)d_in[0];
    const float* cw = (const float*)d_in[1];
    const float* cb = (const float*)d_in[2];
    const float* ow = (const float*)d_in[3];
    float* out = (float*)d_out;
    float* ws  = (float*)d_ws;

    if (ws_size < WS_FLOATS * sizeof(float)) return;

    float* sp   = ws + OFF_SP;
    float* ts   = ws + OFF_TS;
    float* scd  = ws + OFF_SCD;
    u16*   w2m  = (u16*)(ws + OFF_W2M);
    u16*   w2t  = (u16*)(ws + OFF_W2T);
    u16*   hst  = (u16*)(ws + OFF_HST);
    float* op   = ws + OFF_HST;            // overlaps hst (dead by k_gemm)
    u8*    cv   = (u8*)(ws + OFF_CONV);
    u8*    owb  = (u8*)(ws + OFF_OWB);

    k_hstgram<<<dim3(GCHUNKS, cB), 256, 0, stream>>>(hs, hst, sp);
    k_bwcast <<<256, 256, 0, stream>>>(ow, owb);
    k_spred  <<<dim3(24, cB), 256, 0, stream>>>(sp, scd);
    k_smwt   <<<cB, 1024, 0, stream>>>(scd, cw, out + (size_t)cB*cL*cD, w2m, w2t);
    k_conv   <<<dim3(16, 16, cB), 256, 0, stream>>>(hst, w2m, w2t, cb, cv, ts);
    k_gemm   <<<dim3(1, 3, GSPLIT), 512, 0, stream>>>(cv, owb, op);
    k_finish <<<312, 256, 0, stream>>>(ts, op, out);
}

// Round 17
// 187.850 us; speedup vs baseline: 1.0629x; 1.0629x over previous
//
#include <hip/hip_runtime.h>
#include <math.h>

typedef unsigned short u16;
typedef unsigned int   u32;
typedef unsigned char  u8;
typedef __attribute__((ext_vector_type(8))) short short8;
typedef __attribute__((ext_vector_type(4))) float f32x4;
typedef __attribute__((ext_vector_type(4))) unsigned short ushort4_t;

// GeoMamba: B=8, L=39, D=256, K=5, M=252
constexpr int cB   = 8;
constexpr int cL   = 39;
constexpr int cD   = 256;
constexpr int cDD  = 65536;   // D*D
constexpr int cM   = 252;
constexpr int cMM  = 63504;   // M*M
constexpr int PAIRS = cL * cL; // 1521

constexpr int GCHUNKS = 256;   // gram chunks per batch (256 px each)
constexpr int GKP     = 65536; // tile-major K for out-gemm (fp8 bytes per row)
constexpr int CSTEP   = 1024;  // K per gemm block
constexpr int GSPLIT  = 64;    // 64*1024 = 65536; 192 blocks <= 1/CU (no stragglers)
constexpr int PROW    = 40;    // u16 per pixel row of hst
constexpr int WSTR    = 36;    // padded LDS row stride (u16) for conv weight tiles
constexpr int TSTR    = 280;   // gram LDS transpose row stride (u16)

// ---- ws layout (float offsets) ----
constexpr size_t OFF_SP   = 0;                          // gram partials [B][256][1521]
constexpr size_t SZ_SP    = (size_t)cB * GCHUNKS * PAIRS;
constexpr size_t OFF_TS   = 0;                          // overlaps SP (dead after spred)
constexpr size_t OFF_ATTN = OFF_SP + SZ_SP;             // (spare)
constexpr size_t SZ_ATTN  = (size_t)cB * PAIRS;
constexpr size_t OFF_SCD  = OFF_ATTN + SZ_ATTN;         // reduced scores [B][1521]
constexpr size_t SZ_SCD   = (size_t)cB * PAIRS;
constexpr size_t OFF_W2M  = OFF_SCD + SZ_SCD;           // main wts bf16 [B][tap25][oc48][32]
constexpr size_t SZ_W2M   = (size_t)cB * 25 * 48 * 32 / 2;
constexpr size_t OFF_W2T  = OFF_W2M + SZ_W2M;           // tail wts bf16 [B][kc7][oc48][32]
constexpr size_t SZ_W2T   = (size_t)cB * 7 * 48 * 32 / 2;
constexpr size_t OFF_HST  = OFF_W2T + SZ_W2T;           // hst bf16 [B][65536][40]; op overlaps
constexpr size_t SZ_HST   = (size_t)cB * 65536 * PROW / 2;
constexpr size_t SZ_OP    = (size_t)GSPLIT * 312 * 256;
static_assert(SZ_OP <= SZ_HST, "op must fit inside hst region");
constexpr size_t OFF_CONV = OFF_HST + SZ_HST;           // exp(conv) fp8 [312][GKP] tile-major
constexpr size_t SZ_CONV  = (size_t)312 * GKP / 4;
constexpr size_t OFF_OWB  = OFF_CONV + SZ_CONV;         // out_w fp8*256 [256][GKP] tile-major
constexpr size_t SZ_OWB   = (size_t)256 * GKP / 4;
constexpr size_t WS_FLOATS = OFF_OWB + SZ_OWB;          // ~92.5 MB

__device__ inline u16 f2bf(float x) {
    union { float f; unsigned u; } v; v.f = x;
    unsigned r = v.u + 0x7fffu + ((v.u >> 16) & 1u);   // RNE
    return (u16)(r >> 16);
}
__device__ inline u8 f2fp8(float x) {
    return (u8)(__builtin_amdgcn_cvt_pk_fp8_f32(x, x, 0, false) & 0xff);
}

// ---------------------------------------------------------------------------
// K0a: cast out_w*256 -> fp8 e4m3, gathered into tile-major K layout.
// ---------------------------------------------------------------------------
__global__ __launch_bounds__(256) void k_bwcast(const float* __restrict__ ow,
                                                u8* __restrict__ owb) {
    const int o = blockIdx.x;
    const float* src = ow + (size_t)o * cMM;
    u8* dst = owb + (size_t)o * GKP;
    for (int k4 = threadIdx.x; k4 < GKP / 4; k4 += 256) {
        const int k = k4 * 4;
        const int tile = k >> 8, loc = k & 255;
        const int th = tile >> 4, tw = tile & 15;
        const int ph = loc >> 4, pw = loc & 15;
        const int oh = th*16 + ph, owc = tw*16 + pw;
        unsigned r = 0;
        if (oh < cM && owc + 3 < cM) {
            const float4 f = *(const float4*)(src + oh*cM + owc);
            unsigned lo = (unsigned)__builtin_amdgcn_cvt_pk_fp8_f32(f.x*256.f, f.y*256.f, 0, false);
            unsigned hi = (unsigned)__builtin_amdgcn_cvt_pk_fp8_f32(f.z*256.f, f.w*256.f, 0, false);
            r = (lo & 0xffffu) | (hi << 16);
        }
        *(unsigned*)(dst + k) = r;
    }
}

// ---------------------------------------------------------------------------
// K1: fused hst-transpose + MFMA gram (verified round 12/13).
// ---------------------------------------------------------------------------
__global__ __launch_bounds__(256) void k_hstgram(const float* __restrict__ hs,
                                                 u16* __restrict__ hst,
                                                 float* __restrict__ sp) {
    const int b   = blockIdx.y;
    const int ck  = blockIdx.x;
    const int tid = threadIdx.x;
    const int wv = tid >> 6, ln15 = tid & 15, kg4 = (tid & 63) >> 4;
    const int px = ck * 256 + tid;

    __shared__ __align__(16) u8 smem[4 * 48 * 50 * 4];   // 38400 B (R) >= T 26880 B
    u16 (*T)[TSTR] = (u16 (*)[TSTR])smem;

    const float* hb = hs + (size_t)b * (cL * cDD) + px;
    u32 w[20];
    #pragma unroll
    for (int c2 = 0; c2 < 20; ++c2) {
        const int c0 = 2*c2, c1 = 2*c2 + 1;
        const u32 lo = f2bf(hb[(size_t)c0 * cDD]);
        const u32 hi = (c1 < cL) ? (u32)f2bf(hb[(size_t)c1 * cDD]) : 0u;
        w[c2] = lo | (hi << 16);
    }
    // (a) hst store [px][40]
    u16* ob = hst + (size_t)b * (65536 * PROW) + (size_t)px * PROW;
    #pragma unroll
    for (int g = 0; g < 5; ++g) {
        uint4 v;
        v.x = w[g*4 + 0]; v.y = w[g*4 + 1]; v.z = w[g*4 + 2]; v.w = w[g*4 + 3];
        *(uint4*)(ob + g*8) = v;
    }
    // (b) LDS transpose; zero pad rows 39..47
    {
        u16* Tf = (u16*)smem;
        for (int i = tid; i < 9 * TSTR; i += 256) Tf[39*TSTR + i] = 0;
    }
    #pragma unroll
    for (int c2 = 0; c2 < 20; ++c2) {
        T[2*c2][tid] = (u16)w[c2];
        if (2*c2 + 1 < cL) T[2*c2 + 1][tid] = (u16)(w[c2] >> 16);
    }
    __syncthreads();

    f32x4 acc[3][3] = {};
    #pragma unroll
    for (int s = 0; s < 2; ++s) {
        const int pxl = wv*64 + s*32 + kg4*8;
        short8 f[3];
        #pragma unroll
        for (int o = 0; o < 3; ++o)
            f[o] = *(const short8*)&T[o*16 + ln15][pxl];
        #pragma unroll
        for (int oi = 0; oi < 3; ++oi)
            #pragma unroll
            for (int oj = 0; oj < 3; ++oj)
                acc[oi][oj] = __builtin_amdgcn_mfma_f32_16x16x32_bf16(
                    f[oi], f[oj], acc[oi][oj], 0, 0, 0);
    }
    __syncthreads();                       // T reads done; alias as R

    float (*R)[48 * 50] = (float (*)[48 * 50])smem;
    #pragma unroll
    for (int oi = 0; oi < 3; ++oi)
        #pragma unroll
        for (int oj = 0; oj < 3; ++oj)
            #pragma unroll
            for (int r = 0; r < 4; ++r)
                R[wv][(oi*16 + kg4*4 + r)*50 + oj*16 + ln15] = acc[oi][oj][r];
    __syncthreads();

    float* outp = sp + ((size_t)b * GCHUNKS + ck) * PAIRS;
    for (int idx = tid; idx < PAIRS; idx += 256) {
        const int i = idx / 39, j = idx - i * 39;
        const int a = i * 50 + j;
        outp[idx] = R[0][a] + R[1][a] + R[2][a] + R[3][a];
    }
}

// ---------------------------------------------------------------------------
// K1b: parallel reduce of gram partials: scd[b][pair] = sum_c sp[b][c][pair].
// ---------------------------------------------------------------------------
__global__ __launch_bounds__(256) void k_spred(const float* __restrict__ sp,
                                               float* __restrict__ scd) {
    const int b = blockIdx.y, pg = blockIdx.x;
    const int lane = threadIdx.x & 63, cs = threadIdx.x >> 6;
    const int pair = pg*64 + lane;
    float s = 0.f;
    if (pair < PAIRS) {
        const float* base = sp + ((size_t)b*GCHUNKS + cs*64)*PAIRS + pair;
        #pragma unroll 8
        for (int c = 0; c < 64; ++c) s += base[(size_t)c * PAIRS];
    }
    __shared__ float red[4][64];
    red[cs][lane] = s;
    __syncthreads();
    if (threadIdx.x < 64) {
        const int p = pg*64 + threadIdx.x;
        if (p < PAIRS)
            scd[(size_t)b*PAIRS + p] = red[0][threadIdx.x] + red[1][threadIdx.x]
                                     + red[2][threadIdx.x] + red[3][threadIdx.x];
    }
}

// ---------------------------------------------------------------------------
// K2: fused softmax + weight-fold. grid B, 1024 thr.
// ---------------------------------------------------------------------------
__global__ __launch_bounds__(1024) void k_smwt(const float* __restrict__ scd,
                                               const float* __restrict__ cw,
                                               float* __restrict__ outAttn,
                                               u16* __restrict__ w2m,
                                               u16* __restrict__ w2t) {
    const int b = blockIdx.x;
    const int t = threadIdx.x;
    __shared__ float sc[PAIRS];
    for (int idx = t; idx < PAIRS; idx += 1024)
        sc[idx] = scd[(size_t)b*PAIRS + idx] * (1.0f / 256.0f);
    u32* zm = (u32*)(w2m + (size_t)b * 25*48*32);
    u32* zt = (u32*)(w2t + (size_t)b * 7*48*32);
    for (int i = t; i < 25*48*16; i += 1024) zm[i] = 0;
    for (int i = t; i < 7*48*16;  i += 1024) zt[i] = 0;
    __syncthreads();
    if (t < cL) {
        const int i = t;
        float m = -1e30f;
        #pragma unroll
        for (int j = 0; j < cL; ++j) m = fmaxf(m, sc[i*cL + j]);
        float e[cL];
        float sum = 0.f;
        #pragma unroll
        for (int j = 0; j < cL; ++j) { e[j] = expf(sc[i*cL + j] - m); sum += e[j]; }
        const float inv = 1.0f / sum;
        #pragma unroll
        for (int j = 0; j < cL; ++j) {
            const float a = e[j] * inv;
            sc[i*cL + j] = a;
            outAttn[(size_t)b*PAIRS + i*cL + j] = a;
        }
    }
    __syncthreads();
    if (t < cL * 25) {
        const int oc = t / 25, tap = t % 25;
        float c[cL];
        #pragma unroll
        for (int i = 0; i < cL; ++i)
            c[i] = cw[(size_t)oc * (cL*25) + i*25 + tap];
        u16* dm = w2m + ((size_t)(b*25 + tap)*48 + oc)*32;
        u16* dt = w2t + ((size_t)(b*7 + (tap>>2))*48 + oc)*32 + (tap&3)*8;
        for (int j = 0; j < cL; ++j) {
            float a = 0.f;
            #pragma unroll
            for (int i = 0; i < cL; ++i) a = fmaf(c[i], sc[i*cL + j], a);
            if (j < 32) dm[j] = f2bf(a);
            else        dt[j - 32] = f2bf(a);
        }
    }
}

// ---------------------------------------------------------------------------
// K4: conv as dense-K MFMA with double-buffered LDS weight broadcast
// (exact round-15 structure — verified 66.5 us; all swizzles reverted).
// ---------------------------------------------------------------------------
__global__ __launch_bounds__(256, 4) void k_conv(const u16* __restrict__ hst,
                                                 const u16* __restrict__ w2m,
                                                 const u16* __restrict__ w2t,
                                                 const float* __restrict__ cb,
                                                 u8* __restrict__ convout,
                                                 float* __restrict__ tileSumsq) {
    const int b   = blockIdx.z;
    const int gh0 = blockIdx.y * 16, gw0 = blockIdx.x * 16;
    const int tid = threadIdx.x;
    const int wv  = tid >> 6;
    const int ln15 = tid & 15;
    const int kg4  = (tid & 63) >> 4;

    __shared__ u16 P[400 * PROW];      // 32000 B; reused as fp8 staging
    __shared__ u16 W[2][48 * WSTR];    // 2 x 3456 B weight broadcast tiles
    __shared__ float red[4][48];

    const u16* wbm = w2m + (size_t)b * 25*48*32;
    const u16* wbt = w2t + (size_t)b * 7*48*32;
    const bool wact = tid < 192;
    const int  wrow = tid >> 2, wq = tid & 3;

    uint4 wA = {};
    if (wact) wA = *(const uint4*)(wbm + tid*8);

    const u16* hb = hst + (size_t)b * (65536 * PROW);
    for (int c = tid; c < 2000; c += 256) {
        const int p = c / 5, g = c - p*5;
        const int pr = p / 20, pc = p - pr*20;
        const int gh = min(gh0 + pr, 255);
        const size_t pix = (size_t)gh * 256 + gw0 + pc;   // may spill; masked later
        const short8 v = *(const short8*)(hb + pix*PROW + g*8);
        *(short8*)&P[p*PROW + g*8] = v;
    }
    if (wact) {
        *(uint4*)&W[0][wrow*WSTR + wq*8] = wA;
        wA = *(const uint4*)(wbm + 1*48*32 + tid*8);
    }
    __syncthreads();

    f32x4 acc[3][4] = {};

    #pragma unroll
    for (int t = 0; t < 32; ++t) {
        const int cur = t & 1;
        if (t + 1 < 32 && wact)
            *(uint4*)&W[cur ^ 1][wrow*WSTR + wq*8] = wA;
        if (t + 2 < 32 && wact) {
            const int c2 = t + 2;
            const u16* ws = (c2 < 25) ? (wbm + (size_t)c2 * 48*32)
                                      : (wbt + (size_t)(c2 - 25) * 48*32);
            wA = *(const uint4*)(ws + tid*8);
        }
        short8 af0 = *(const short8*)&W[cur][( 0 + ln15)*WSTR + kg4*8];
        short8 af1 = *(const short8*)&W[cur][(16 + ln15)*WSTR + kg4*8];
        short8 af2 = *(const short8*)&W[cur][(32 + ln15)*WSTR + kg4*8];
        if (t < 25) {
            const int kh = t / 5, kw = t - (t/5)*5;
            #pragma unroll
            for (int pt = 0; pt < 4; ++pt) {
                const int p = (wv*4 + pt + kh)*20 + ln15 + kw;
                const short8 bfr = *(const short8*)&P[p*PROW + kg4*8];
                acc[0][pt] = __builtin_amdgcn_mfma_f32_16x16x32_bf16(af0, bfr, acc[0][pt], 0, 0, 0);
                acc[1][pt] = __builtin_amdgcn_mfma_f32_16x16x32_bf16(af1, bfr, acc[1][pt], 0, 0, 0);
                acc[2][pt] = __builtin_amdgcn_mfma_f32_16x16x32_bf16(af2, bfr, acc[2][pt], 0, 0, 0);
            }
        } else {
            int tap = (t - 25)*4 + kg4;
            if (tap > 24) tap = 24;
            const int kh = tap / 5, kw = tap - kh*5;
            #pragma unroll
            for (int pt = 0; pt < 4; ++pt) {
                const int p = (wv*4 + pt + kh)*20 + ln15 + kw;
                const short8 bfr = *(const short8*)&P[p*PROW + 32];
                acc[0][pt] = __builtin_amdgcn_mfma_f32_16x16x32_bf16(af0, bfr, acc[0][pt], 0, 0, 0);
                acc[1][pt] = __builtin_amdgcn_mfma_f32_16x16x32_bf16(af1, bfr, acc[1][pt], 0, 0, 0);
                acc[2][pt] = __builtin_amdgcn_mfma_f32_16x16x32_bf16(af2, bfr, acc[2][pt], 0, 0, 0);
            }
        }
        __syncthreads();
    }

    u8* E = (u8*)P;                   // E[oc][256] fp8 staging

    float ss[3][4];
    #pragma unroll
    for (int o = 0; o < 3; ++o)
        #pragma unroll
        for (int r = 0; r < 4; ++r) ss[o][r] = 0.f;

    const int tile = blockIdx.y * 16 + blockIdx.x;
    const int ow = gw0 + ln15;
    #pragma unroll
    for (int o = 0; o < 3; ++o) {
        #pragma unroll
        for (int r = 0; r < 4; ++r) {
            const int oc = o*16 + kg4*4 + r;
            const float bias = (oc < cL) ? cb[oc] : 0.f;
            #pragma unroll
            for (int pt = 0; pt < 4; ++pt) {
                const int oh = gh0 + wv*4 + pt;
                const int loc = (wv*4 + pt)*16 + ln15;
                u8 val = 0;
                if (oc < cL && oh < cM && ow < cM) {
                    const float e = __expf(acc[o][pt][r] + bias);
                    if (ow <= oh) val = f2fp8(e);
                    ss[o][r] += e * e;
                }
                if (oc < cL) E[oc*256 + loc] = val;
            }
        }
    }
    __syncthreads();

    for (int c = tid; c < cL*16; c += 256) {
        const int oc = c >> 4, seg = c & 15;
        const uint4 v = *(const uint4*)&E[oc*256 + seg*16];
        *(uint4*)&convout[(size_t)(b*cL + oc)*GKP + tile*256 + seg*16] = v;
    }

    #pragma unroll
    for (int o = 0; o < 3; ++o) {
        #pragma unroll
        for (int r = 0; r < 4; ++r) {
            float v = ss[o][r];
            v += __shfl_xor(v, 1);
            v += __shfl_xor(v, 2);
            v += __shfl_xor(v, 4);
            v += __shfl_xor(v, 8);
            if (ln15 == 0) red[wv][o*16 + kg4*4 + r] = v;
        }
    }
    __syncthreads();
    if (tid < cL) {
        tileSumsq[((size_t)b*256 + tile)*cL + tid] =
            red[0][tid] + red[1][tid] + red[2][tid] + red[3][tid];
    }
}

// ---------------------------------------------------------------------------
// K5: fp8 MFMA out-GEMM. grid (1, 3, 64), 512 thr; block tile 128x256,
// wave tile 64x64; CSTEP=1024 (192 blocks <= 1/CU, no straggler serialization;
// halved K-split partial traffic).
// ---------------------------------------------------------------------------
__global__ __launch_bounds__(512) void k_gemm(const u8* __restrict__ A,
                                              const u8* __restrict__ Bw,
                                              float* __restrict__ op) {
    const int mt = blockIdx.y, z = blockIdx.z;
    const int tid = threadIdx.x;
    const int wid = tid >> 6, lane = tid & 63;
    const int ln15 = lane & 15, kg4 = lane >> 4;
    const int wm = wid >> 2, wn = wid & 3;

    __shared__ u8 As[2][128*80];
    __shared__ u8 Bs[2][256*80];

    const int mbase = mt * 128;
    const int ra = tid >> 2, sl = tid & 3;
    const int arow = mbase + ra;
    const int aro = (arow < 312) ? arow : 0;
    const u8* Ap  = A  + (size_t)aro * GKP        + z*CSTEP + sl*16;
    const u8* Bp0 = Bw + (size_t)ra * GKP         + z*CSTEP + sl*16;
    const u8* Bp1 = Bw + (size_t)(128 + ra) * GKP + z*CSTEP + sl*16;

    uint4 pa  = *(const uint4*)Ap;
    uint4 pb0 = *(const uint4*)Bp0;
    uint4 pb1 = *(const uint4*)Bp1;

    f32x4 acc[4][4] = {};

    for (int s = 0; s < CSTEP/64; ++s) {
        const int cur = s & 1;
        __syncthreads();
        *(uint4*)&As[cur][ra*80 + sl*16]        = pa;
        *(uint4*)&Bs[cur][ra*80 + sl*16]        = pb0;
        *(uint4*)&Bs[cur][(128 + ra)*80 + sl*16] = pb1;
        __syncthreads();
        if (s + 1 < CSTEP/64) {
            const int off = (s + 1) * 64;
            pa  = *(const uint4*)(Ap + off);
            pb0 = *(const uint4*)(Bp0 + off);
            pb1 = *(const uint4*)(Bp1 + off);
        }
        #pragma unroll
        for (int kc = 0; kc < 2; ++kc) {
            long af[4], bf[4];
            #pragma unroll
            for (int fm = 0; fm < 4; ++fm)
                af[fm] = *(const long*)&As[cur][(wm*64 + fm*16 + ln15)*80 + kc*32 + kg4*8];
            #pragma unroll
            for (int fn = 0; fn < 4; ++fn)
                bf[fn] = *(const long*)&Bs[cur][(wn*64 + fn*16 + ln15)*80 + kc*32 + kg4*8];
            #pragma unroll
            for (int fm = 0; fm < 4; ++fm)
                #pragma unroll
                for (int fn = 0; fn < 4; ++fn)
                    acc[fm][fn] = __builtin_amdgcn_mfma_f32_16x16x32_fp8_fp8(
                        af[fm], bf[fn], acc[fm][fn], 0, 0, 0);
        }
    }

    #pragma unroll
    for (int fm = 0; fm < 4; ++fm) {
        #pragma unroll
        for (int r = 0; r < 4; ++r) {
            const int row = mbase + wm*64 + fm*16 + kg4*4 + r;
            if (row < 312) {
                #pragma unroll
                for (int fn = 0; fn < 4; ++fn) {
                    const int col = wn*64 + fn*16 + ln15;
                    op[((size_t)z*312 + row)*256 + col] = acc[fm][fn][r];
                }
            }
        }
    }
}

// ---------------------------------------------------------------------------
// K5b: fused norm + finish. grid 312.
// ---------------------------------------------------------------------------
__global__ __launch_bounds__(256) void k_finish(const float* __restrict__ ts,
                                                const float* __restrict__ op,
                                                float* __restrict__ out) {
    const int row = blockIdx.x;                // b*39 + l
    const int b = row / cL, l = row - b*cL;
    const int tid = threadIdx.x;

    float v = ts[((size_t)b*256 + tid)*cL + l];
    for (int off = 32; off; off >>= 1) v += __shfl_down(v, off, 64);
    __shared__ float r[4];
    __shared__ float nrm;
    if ((tid & 63) == 0) r[tid >> 6] = v;
    __syncthreads();
    if (tid == 0) nrm = sqrtf(r[0] + r[1] + r[2] + r[3]) * 256.0f;
    __syncthreads();

    const int idx = row * 256 + tid;
    float s = 0.f;
    for (int z = 0; z < GSPLIT; ++z) s += op[(size_t)z * (312*256) + idx];
    out[idx] = s / nrm;
}

// ---------------------------------------------------------------------------
extern "C" void kernel_launch(void* const* d_in, const int* in_sizes, int n_in,
                              void* d_out, int out_size, void* d_ws, size_t ws_size,
                              hipStream_t stream) {
    const float* hs = (const float*)d_in[0];
    const float* cw = (const float*)d_in[1];
    const float* cb = (const float*)d_in[2];
    const float* ow = (const float*)d_in[3];
    float* out = (float*)d_out;
    float* ws  = (float*)d_ws;

    if (ws_size < WS_FLOATS * sizeof(float)) return;

    float* sp   = ws + OFF_SP;
    float* ts   = ws + OFF_TS;
    float* scd  = ws + OFF_SCD;
    u16*   w2m  = (u16*)(ws + OFF_W2M);
    u16*   w2t  = (u16*)(ws + OFF_W2T);
    u16*   hst  = (u16*)(ws + OFF_HST);
    float* op   = ws + OFF_HST;            // overlaps hst (dead by k_gemm)
    u8*    cv   = (u8*)(ws + OFF_CONV);
    u8*    owb  = (u8*)(ws + OFF_OWB);

    k_hstgram<<<dim3(GCHUNKS, cB), 256, 0, stream>>>(hs, hst, sp);
    k_bwcast <<<256, 256, 0, stream>>>(ow, owb);
    k_spred  <<<dim3(24, cB), 256, 0, stream>>>(sp, scd);
    k_smwt   <<<cB, 1024, 0, stream>>>(scd, cw, out + (size_t)cB*cL*cD, w2m, w2t);
    k_conv   <<<dim3(16, 16, cB), 256, 0, stream>>>(hst, w2m, w2t, cb, cv, ts);
    k_gemm   <<<dim3(1, 3, GSPLIT), 512, 0, stream>>>(cv, owb, op);
    k_finish <<<312, 256, 0, stream>>>(ts, op, out);
}